// Round 19
// baseline (1242.613 us; speedup 1.0000x reference)
//
#include <hip/hip_runtime.h>
#include <hip/hip_bf16.h>
#include <hip/hip_fp8.h>

typedef __bf16 bf16_t;
typedef bf16_t bf16x8 __attribute__((ext_vector_type(8)));
typedef float f32x4 __attribute__((ext_vector_type(4)));
typedef float f32x16 __attribute__((ext_vector_type(16)));
typedef int   i32x4  __attribute__((ext_vector_type(4)));
typedef int   i32x8  __attribute__((ext_vector_type(8)));

#define N_ROWS 4096
#define DIM    2048
#define VOCAB  65536
#define IGN    (-100)

// ---------------- MX-fp8 128x128 GEMM, BK=128, 4-tile-deep pipeline --------
#define BM 128
#define BN 128
#define BK 128            // fp8 elems (=bytes) per K-tile
#define NT (DIM / BK)     // 16 K-tiles
#define NUNITS (4 * NT)   // 64 stage units (8KB each)
#define SCALE1 0x7F7F7F7F // e8m0 = 127 -> 1.0 in every byte

#define GLOAD_LDS16(gp, lp)                                                  \
  __builtin_amdgcn_global_load_lds(                                          \
      (const __attribute__((address_space(1))) void*)(gp),                   \
      (__attribute__((address_space(3))) void*)(lp), 16, 0, 0)

// fp32 -> fp8 e4m3 (OCP) with pre-scale; 16 elems/thread/iter
__global__ __launch_bounds__(256)
void cvt_fp8(const float* __restrict__ src, unsigned char* __restrict__ dst,
             long n16, float scale) {
  long i = (long)blockIdx.x * 256 + threadIdx.x;
  long stride = (long)gridDim.x * 256;
  for (; i < n16; i += stride) {
    const float4* s = reinterpret_cast<const float4*>(src) + i * 4;
    union { unsigned char b[16]; i32x4 v; } o;
#pragma unroll
    for (int q = 0; q < 4; ++q) {
      float4 a = s[q];
      o.b[q * 4 + 0] = __hip_fp8_e4m3(a.x * scale).__x;
      o.b[q * 4 + 1] = __hip_fp8_e4m3(a.y * scale).__x;
      o.b[q * 4 + 2] = __hip_fp8_e4m3(a.z * scale).__x;
      o.b[q * 4 + 3] = __hip_fp8_e4m3(a.w * scale).__x;
    }
    *reinterpret_cast<i32x4*>(dst + i * 16) = o.v;
  }
}

// 128x128 tile, BK=128, 8 waves (2M x 4N, each 64x32 out), MX-fp8 MFMA.
// PIPELINE DEPTH (this round's change): R10..R18 all had ~1-phase
// stage->wait distance (~600-800cyc) < loaded HBM latency (~900-2000cyc)
// -> every wave stalled ~800cyc/tile at vmcnt. Now: LDS 128KB = 16 slots
// x 8KB = 4-tile rotation (slot = ug mod 16; tile T's quad = (T&3)*4).
// At tile T stage tile T+3's 4 units; tile top waits vmcnt(8) (drains T's
// units, leaves T+1/T+2 in flight) -> issue-to-wait ~2.3 tiles (~1500+
// cyc) > HBM latency. ONE barrier per tile.
// Slot safety (one-barrier proof): T's stage writes quad (T+3)mod4 =
// (T-1)mod4; T-1's reads drained per-wave by lgkm(0) before its last
// MFMA, and the stage happens after T's tile-top barrier which is after
// ALL waves finished T-1 -> safe. T's reads (quad T mod 4) vs stages of
// quads (T+1),(T+2) mod 4: disjoint. Tail: vmcnt(4) at NT-2, (0) at NT-1.
// Unit u of tile T: 0=A[k0:64], 1=B[k0:64], 2=A[k64:128], 3=B[k64:128];
// unit = 8 windows of 1KB (16 rows x 64B); slot i of window holds granule
// tau(i)=(i&~3)|((i&3)^((i>>3)&3)); staging = linear LDS dest (one gload
// per wave per unit: 512 thr x 16B = 8KB) + window-permuted source;
// frag reads swizzle chunk c -> c^((l31>>1)&3).
// Per tile per wave: 12 ds_read (ks0: B,A,A = 6; ks1: 6), lgkm(6) gates
// ks0 MFMA (2), lgkm(0) gates ks1 MFMA (2). 1 wg/CU, 8 waves = 2/SIMD.
__global__ __launch_bounds__(512, 2)
void lce_gemm_fp8(const unsigned char* __restrict__ E8,
                  const unsigned char* __restrict__ C8,
                  float* __restrict__ sumexp) {
  extern __shared__ unsigned char lds[];  // 131072
  const int tid = threadIdx.x;
  const int lane = tid & 63, wid = tid >> 6;
  const int wr = wid >> 2, wc = wid & 3;      // 2M x 4N waves, 64x32 each
  const int l31 = lane & 31, lh = lane >> 5;

  // R14 row-fast XCD swizzle (proven best-time)
  const int bid = blockIdx.x;
  const int wg = (bid & 7) * 2048 + (bid >> 3);   // 8 x 2048 = 16384 wgs
  const int brow = (wg & 31) * BM;                // 32 row tiles
  const int bcol = (wg >> 5) * BN;                // 512 col tiles

  // ---- staging: ONE granule of 16B per thread (512 thr = 8KB unit) --------
  const int g0 = wid * 64 + lane;         // granule 0..511
  const int prel0 = g0 * 16;              // linear LDS dest
  auto mkgoff = [&](int g) {              // window-permuted global source
    int w = g >> 6, i = g & 63;
    return (size_t)(w * 16 + (i >> 2)) * DIM +
           (size_t)((((i & 3) ^ ((i >> 3) & 3)) << 4));
  };
  const size_t goff0 = mkgoff(g0);

  const unsigned char* Ebase = E8 + (size_t)brow * DIM;
  const unsigned char* Cbase = C8 + (size_t)bcol * DIM;

  auto stage = [&](int ug) {   // ug = global unit index [0, NUNITS)
    const unsigned char* gb = ((ug & 1) ? Cbase : Ebase) +
                              (ug >> 2) * BK + ((ug >> 1) & 1) * 64;
    unsigned char* lb = lds + (ug & 15) * 8192;     // slot = ug mod 16
    GLOAD_LDS16(gb + goff0, lb + prel0);
  };

  // ---- fragment read: slab s (rows s*32+l31), swizzled chunks -------------
  const int sw = (l31 >> 1) & 3;
  auto read_frag = [&](const unsigned char* U, int s) -> i32x8 {
    const unsigned char* p =
        U + s * 2048 + (l31 >> 4) * 1024 + (l31 & 15) * 64;
    i32x4 lo = *reinterpret_cast<const i32x4*>(p + (((lh * 2)     ^ sw) << 4));
    i32x4 hi = *reinterpret_cast<const i32x4*>(p + (((lh * 2 + 1) ^ sw) << 4));
    return __builtin_shufflevector(lo, hi, 0, 1, 2, 3, 4, 5, 6, 7);
  };

  f32x16 acc[2];
#pragma unroll
  for (int mi = 0; mi < 2; ++mi)
#pragma unroll
    for (int r = 0; r < 16; ++r) acc[mi][r] = 0.f;

  // ---- prologue: stage tiles 0,1,2 (units 0..11) --------------------------
#pragma unroll
  for (int h = 0; h < 12; ++h) stage(h);

  i32x8 af0[2], af1[2], bf0, bf1;

  for (int T = 0; T < NT; ++T) {
    // step 1: wait for tile T's units, publish to all waves
    if (T < NT - 2)      asm volatile("s_waitcnt vmcnt(8)" ::: "memory");
    else if (T == NT - 2) asm volatile("s_waitcnt vmcnt(4)" ::: "memory");
    else                  asm volatile("s_waitcnt vmcnt(0)" ::: "memory");
    __builtin_amdgcn_s_barrier();

    const unsigned char* base = lds + (T & 3) * 32768;
    const unsigned char* aU0 = base;
    const unsigned char* bU0 = base + 8192;
    const unsigned char* aU1 = base + 16384;
    const unsigned char* bU1 = base + 24576;

    // step 2: issue all 12 ds_reads (ks0 group first; order pinned)
    bf0 = read_frag(bU0, wc);
#pragma unroll
    for (int mi = 0; mi < 2; ++mi) af0[mi] = read_frag(aU0, wr * 2 + mi);
    __builtin_amdgcn_sched_barrier(0);
    bf1 = read_frag(bU1, wc);
#pragma unroll
    for (int mi = 0; mi < 2; ++mi) af1[mi] = read_frag(aU1, wr * 2 + mi);
    __builtin_amdgcn_sched_barrier(0);

    // step 3: stage tile T+3 (deep prefetch; slots of quad (T-1)mod4)
    {
      const int ug0 = 4 * (T + 3);
#pragma unroll
      for (int u = 0; u < 4; ++u)
        if (ug0 + u < NUNITS) stage(ug0 + u);
    }

    // step 4: ks0 MFMA under ks1-reads-in-flight
    asm volatile("s_waitcnt lgkmcnt(6)" ::: "memory");
    __builtin_amdgcn_sched_barrier(0);
    __builtin_amdgcn_s_setprio(1);
#pragma unroll
    for (int mi = 0; mi < 2; ++mi)
      acc[mi] = __builtin_amdgcn_mfma_scale_f32_32x32x64_f8f6f4(
          af0[mi], bf0, acc[mi], 0, 0, 0, SCALE1, 0, SCALE1);
    __builtin_amdgcn_s_setprio(0);

    // step 5: ks1 MFMA
    asm volatile("s_waitcnt lgkmcnt(0)" ::: "memory");
    __builtin_amdgcn_sched_barrier(0);
    __builtin_amdgcn_s_setprio(1);
#pragma unroll
    for (int mi = 0; mi < 2; ++mi)
      acc[mi] = __builtin_amdgcn_mfma_scale_f32_32x32x64_f8f6f4(
          af1[mi], bf1, acc[mi], 0, 0, 0, SCALE1, 0, SCALE1);
    __builtin_amdgcn_s_setprio(0);
  }

  // ---- epilogue: per-row sum of exp(logit); wave covers cols wc*32.. ------
  // 32x32 C/D: col = lane&31, row = (reg&3) + 8*(reg>>2) + 4*(lane>>5).
  // Undo the C*8 pre-scale: logit = acc * 0.125.
#pragma unroll
  for (int mi = 0; mi < 2; ++mi) {
    float p[16];
#pragma unroll
    for (int r = 0; r < 16; ++r) p[r] = __expf(acc[mi][r] * 0.125f);
#pragma unroll
    for (int m = 1; m < 32; m <<= 1)
#pragma unroll
      for (int r = 0; r < 16; ++r) p[r] += __shfl_xor(p[r], m, 64);
    if (l31 == 0) {
#pragma unroll
      for (int r = 0; r < 16; ++r) {
        const int row = brow + wr * 64 + mi * 32 + (r & 3) + 8 * (r >> 2) + 4 * lh;
        atomicAdd(&sumexp[row], p[r]);
      }
    }
  }
}

// ---------------- fallback path (fp32 reg-staged, 128^2 tile) --------------
#define FBM 128
#define FBN 128
#define FBK 64
#define FNK (DIM / FBK)
#define FTHREADS 512

__global__ __launch_bounds__(FTHREADS, 4)
void lce_gemm_f32(const float* __restrict__ E, const float* __restrict__ C,
                  float* __restrict__ sumexp) {
  extern __shared__ unsigned char lds[];
  const int tid  = threadIdx.x;
  const int brow = blockIdx.x * FBM;
  const int bcol = blockIdx.y * FBN;

  float4 ra[4], rb[4];
  auto ld = [&](int k0) {
#pragma unroll
    for (int i = 0; i < 4; ++i) {
      int f = tid + i * FTHREADS;
      int r = f >> 4;
      int c = (f & 15) << 2;
      ra[i] = *reinterpret_cast<const float4*>(&E[(size_t)(brow + r) * DIM + k0 + c]);
      rb[i] = *reinterpret_cast<const float4*>(&C[(size_t)(bcol + r) * DIM + k0 + c]);
    }
  };
  auto st = [&](int buf) {
    unsigned char* a = lds + buf * 32768;
    unsigned char* b = a + 16384;
#pragma unroll
    for (int i = 0; i < 4; ++i) {
      int f  = tid + i * FTHREADS;
      int r  = f >> 4;
      int cbb = (f & 15) << 3;
      int off = r * 128 + (cbb ^ ((r & 7) << 4));
      union { bf16_t h[4]; unsigned long long u; } pa, pb;
      pa.h[0] = (bf16_t)ra[i].x; pa.h[1] = (bf16_t)ra[i].y;
      pa.h[2] = (bf16_t)ra[i].z; pa.h[3] = (bf16_t)ra[i].w;
      pb.h[0] = (bf16_t)rb[i].x; pb.h[1] = (bf16_t)rb[i].y;
      pb.h[2] = (bf16_t)rb[i].z; pb.h[3] = (bf16_t)rb[i].w;
      *reinterpret_cast<unsigned long long*>(a + off) = pa.u;
      *reinterpret_cast<unsigned long long*>(b + off) = pb.u;
    }
  };

  f32x4 acc[4][2];
#pragma unroll
  for (int mi = 0; mi < 4; ++mi)
#pragma unroll
    for (int ni = 0; ni < 2; ++ni) acc[mi][ni] = (f32x4){0.f, 0.f, 0.f, 0.f};

  const int lane = tid & 63, wid = tid >> 6;
  const int wr = wid >> 2, wc = wid & 3;
  const int l15 = lane & 15, lg = lane >> 4;
  const int swz = (l15 & 7) << 4;

  auto comp = [&](int buf) {
    const unsigned char* a = lds + buf * 32768;
    const unsigned char* b = a + 16384;
#pragma unroll
    for (int kk = 0; kk < 2; ++kk) {
      const int cbase = (kk * 64 + lg * 16) ^ swz;
      bf16x8 af[4], bfr[2];
#pragma unroll
      for (int mi = 0; mi < 4; ++mi)
        af[mi] = *reinterpret_cast<const bf16x8*>(
            a + (wr * 64 + mi * 16 + l15) * 128 + cbase);
#pragma unroll
      for (int ni = 0; ni < 2; ++ni)
        bfr[ni] = *reinterpret_cast<const bf16x8*>(
            b + (wc * 32 + ni * 16 + l15) * 128 + cbase);
#pragma unroll
      for (int mi = 0; mi < 4; ++mi)
#pragma unroll
        for (int ni = 0; ni < 2; ++ni)
          acc[mi][ni] = __builtin_amdgcn_mfma_f32_16x16x32_bf16(
              af[mi], bfr[ni], acc[mi][ni], 0, 0, 0);
    }
  };

  ld(0);
  st(0);
  for (int kt = 0; kt < FNK; ++kt) {
    __syncthreads();
    if (kt + 1 < FNK) ld((kt + 1) * FBK);
    comp(kt & 1);
    if (kt + 1 < FNK) st((kt + 1) & 1);
  }

#pragma unroll
  for (int mi = 0; mi < 4; ++mi) {
    float p[4];
#pragma unroll
    for (int j = 0; j < 4; ++j)
      p[j] = __expf(acc[mi][0][j]) + __expf(acc[mi][1][j]);
#pragma unroll
    for (int m = 1; m < 16; m <<= 1)
#pragma unroll
      for (int j = 0; j < 4; ++j) p[j] += __shfl_xor(p[j], m, 64);
    if (l15 == 0) {
      int row = brow + wr * 64 + mi * 16 + lg * 4;
#pragma unroll
      for (int j = 0; j < 4; ++j) atomicAdd(&sumexp[row + j], p[j]);
    }
  }
}

// ---------------- exact fp32 target logit, one wave per row ----------------
__global__ __launch_bounds__(256)
void lce_tgt(const float* __restrict__ E, const float* __restrict__ C,
             const int* __restrict__ T, float* __restrict__ tgt) {
  int w = (int)((blockIdx.x * blockDim.x + threadIdx.x) >> 6);
  int lane = threadIdx.x & 63;
  if (w >= N_ROWS) return;
  int t = T[w];
  float s = 0.f;
  if (t != IGN) {
    const float4* er = reinterpret_cast<const float4*>(E + (size_t)w * DIM);
    const float4* cr = reinterpret_cast<const float4*>(C + (size_t)t * DIM);
#pragma unroll
    for (int i = 0; i < DIM / 4 / 64; ++i) {
      float4 a = er[lane + i * 64];
      float4 b = cr[lane + i * 64];
      s = fmaf(a.x, b.x, s); s = fmaf(a.y, b.y, s);
      s = fmaf(a.z, b.z, s); s = fmaf(a.w, b.w, s);
    }
#pragma unroll
    for (int m = 1; m < 64; m <<= 1) s += __shfl_xor(s, m, 64);
  }
  if (lane == 0) tgt[w] = s;
}

// ---------------- final scalar reduce --------------------------------------
__global__ __launch_bounds__(256)
void lce_finalize(const float* __restrict__ sumexp, const float* __restrict__ tgt,
                  const int* __restrict__ T, float* __restrict__ out) {
  int tid = threadIdx.x;
  float nll = 0.f, cnt = 0.f;
  for (int n = tid; n < N_ROWS; n += 256) {
    if (T[n] != IGN) {
      nll += logf(sumexp[n]) - tgt[n];
      cnt += 1.f;
    }
  }
#pragma unroll
  for (int m = 1; m < 64; m <<= 1) {
    nll += __shfl_xor(nll, m, 64);
    cnt += __shfl_xor(cnt, m, 64);
  }
  __shared__ float sn[4], sc[4];
  if ((tid & 63) == 0) { sn[tid >> 6] = nll; sc[tid >> 6] = cnt; }
  __syncthreads();
  if (tid == 0) {
    float a = 0.f, b = 0.f;
#pragma unroll
    for (int i = 0; i < 4; ++i) { a += sn[i]; b += sc[i]; }
    out[0] = a / fmaxf(b, 1.f);
  }
}

extern "C" void kernel_launch(void* const* d_in, const int* in_sizes, int n_in,
                              void* d_out, int out_size, void* d_ws, size_t ws_size,
                              hipStream_t stream) {
  const float* E = (const float*)d_in[0];
  const float* C = (const float*)d_in[1];
  const int*   T = (const int*)d_in[2];
  float* out = (float*)d_out;

  unsigned char* ws = (unsigned char*)d_ws;
  float* sumexp = (float*)ws;                        // 16 KB
  float* tgt    = (float*)(ws + 16384);              // 16 KB
  unsigned char* E8 = ws + 32768;                    // 8 MB
  unsigned char* C8 = E8 + (size_t)N_ROWS * DIM;     // 128 MB

  const size_t need = 32768 + (size_t)N_ROWS * DIM + (size_t)VOCAB * DIM;

  hipMemsetAsync(sumexp, 0, N_ROWS * sizeof(float), stream);

  if (ws_size >= need) {
    cvt_fp8<<<2048, 256, 0, stream>>>(E, E8, (long)N_ROWS * DIM / 16, 1.0f);
    cvt_fp8<<<2048, 256, 0, stream>>>(C, C8, (long)VOCAB * DIM / 16, 8.0f);
    lce_gemm_fp8<<<dim3((N_ROWS / BM) * (VOCAB / BN)), 512, 131072, stream>>>(E8, C8, sumexp);
  } else {
    lce_gemm_f32<<<dim3(N_ROWS / FBM, VOCAB / FBN), FTHREADS, 65536, stream>>>(E, C, sumexp);
  }

  lce_tgt<<<dim3((N_ROWS * 64) / 256), 256, 0, stream>>>(E, C, T, tgt);
  lce_finalize<<<dim3(1), 256, 0, stream>>>(sumexp, tgt, T, out);
}

// Round 20
// 910.727 us; speedup vs baseline: 1.3644x; 1.3644x over previous
//
#include <hip/hip_runtime.h>
#include <hip/hip_bf16.h>
#include <hip/hip_fp8.h>

typedef __bf16 bf16_t;
typedef bf16_t bf16x8 __attribute__((ext_vector_type(8)));
typedef float f32x4 __attribute__((ext_vector_type(4)));
typedef float f32x16 __attribute__((ext_vector_type(16)));
typedef int   i32x4  __attribute__((ext_vector_type(4)));
typedef int   i32x8  __attribute__((ext_vector_type(8)));

#define N_ROWS 4096
#define DIM    2048
#define VOCAB  65536
#define IGN    (-100)

// ---------------- MX-fp8 128x128 GEMM, BK=128, 3 wgs/CU --------------------
#define BM 128
#define BN 128
#define BK 128            // fp8 elems (=bytes) per K-tile
#define NT (DIM / BK)     // 16 K-tiles
#define NUNITS (4 * NT)   // 64 stage units (8KB each)
#define NSLOT 6           // 6-slot rotation -> 48KB LDS -> 3 wgs/CU
#define SCALE1 0x7F7F7F7F // e8m0 = 127 -> 1.0 in every byte

#define GLOAD_LDS16(gp, lp)                                                  \
  __builtin_amdgcn_global_load_lds(                                          \
      (const __attribute__((address_space(1))) void*)(gp),                   \
      (__attribute__((address_space(3))) void*)(lp), 16, 0, 0)

// fp32 -> fp8 e4m3 (OCP) with pre-scale; 16 elems/thread/iter
__global__ __launch_bounds__(256)
void cvt_fp8(const float* __restrict__ src, unsigned char* __restrict__ dst,
             long n16, float scale) {
  long i = (long)blockIdx.x * 256 + threadIdx.x;
  long stride = (long)gridDim.x * 256;
  for (; i < n16; i += stride) {
    const float4* s = reinterpret_cast<const float4*>(src) + i * 4;
    union { unsigned char b[16]; i32x4 v; } o;
#pragma unroll
    for (int q = 0; q < 4; ++q) {
      float4 a = s[q];
      o.b[q * 4 + 0] = __hip_fp8_e4m3(a.x * scale).__x;
      o.b[q * 4 + 1] = __hip_fp8_e4m3(a.y * scale).__x;
      o.b[q * 4 + 2] = __hip_fp8_e4m3(a.z * scale).__x;
      o.b[q * 4 + 3] = __hip_fp8_e4m3(a.w * scale).__x;
    }
    *reinterpret_cast<i32x4*>(dst + i * 16) = o.v;
  }
}

// 128x128 tile, BK=128, 4 waves (2M x 2N, each 64x64 out), MX-fp8 MFMA
// (32x32x64, unity scales; C pre-scaled x8, undone via acc*0.125).
// OCCUPANCY (this round's change): R14's wall decomposes as MFMA 1100 +
// LDS 1280 + VALU 500 cyc per tile-step vs 3520 observed -- the phases
// SERIALIZE within-wave because only 2 waves/SIMD are resident (both
// barrier-synced in the same phase). LDS 64KB->48KB (NSLOT 8->6) gives
// 3 wgs/CU = 3 waves/SIMD (m97/m114: the overlap that made 874 TF was
// ~3 blocks/CU wave-level co-scheduling). VGPR ~84 x 3 = 252 <= 256 ok.
// Slot = ug mod 6. Tile T's units 4T+u -> slots (4T+u)%6.
// P0: vmcnt(4); barrier; read u0,u1; stage T+1's u0,u1 (slots (4T+4,5)%6,
//     last used by tile T-2 -- drained); lgkm(0); 4 MFMA.
// P1: vmcnt(4) [vmcnt(0) at T=NT-1]; barrier; read u2,u3; stage T+1's
//     u2,u3 (slots (4T,4T+1)%6 = T's u0,u1 -- safe: P0's phase-top
//     barrier of P1 comes after all waves drained u0,u1 reads);
//     lgkm(0); 4 MFMA.
// vmcnt: 2 gloads/unit, 4/phase. Prologue stages u0..u5 (12 loads),
// vmcnt(4) leaves tile1's u0,u1 in flight. Steady state: phase-top
// outstanding 8, vmcnt(4) drains the 4 oldest (= the units this phase
// reads). Unit layout / tau-permute / frag-read swizzle: as R10-R14.
__global__ __launch_bounds__(256, 3)
void lce_gemm_fp8(const unsigned char* __restrict__ E8,
                  const unsigned char* __restrict__ C8,
                  float* __restrict__ sumexp) {
  extern __shared__ unsigned char lds[];  // 49152
  const int tid = threadIdx.x;
  const int lane = tid & 63, wid = tid >> 6;
  const int wr = wid >> 1, wc = wid & 1;      // 2M x 2N waves
  const int l31 = lane & 31, lh = lane >> 5;

  // R14 row-fast XCD swizzle (proven best-time)
  const int bid = blockIdx.x;
  const int wg = (bid & 7) * 2048 + (bid >> 3);   // 8 x 2048 = 16384 wgs
  const int brow = (wg & 31) * BM;                // 32 row tiles
  const int bcol = (wg >> 5) * BN;                // 512 col tiles

  // ---- staging: per-thread 2 granules of 16B ------------------------------
  const int g0 = wid * 64 + lane;         // granule 0..255
  const int g1 = 256 + g0;                // granule 256..511
  const int prel0 = g0 * 16;              // linear LDS dest (8KB unit)
  const int prel1 = g1 * 16;
  auto mkgoff = [&](int g) {              // window-permuted global source
    int w = g >> 6, i = g & 63;
    return (size_t)(w * 16 + (i >> 2)) * DIM +
           (size_t)((((i & 3) ^ ((i >> 3) & 3)) << 4));
  };
  const size_t goff0 = mkgoff(g0), goff1 = mkgoff(g1);

  const unsigned char* Ebase = E8 + (size_t)brow * DIM;
  const unsigned char* Cbase = C8 + (size_t)bcol * DIM;

  auto stage = [&](int ug) {   // ug = global unit index [0, NUNITS)
    const unsigned char* gb = ((ug & 1) ? Cbase : Ebase) +
                              (ug >> 2) * BK + ((ug >> 1) & 1) * 64;
    unsigned char* lb = lds + (ug % NSLOT) * 8192;  // slot = ug mod 6
    GLOAD_LDS16(gb + goff0, lb + prel0);
    GLOAD_LDS16(gb + goff1, lb + prel1);
  };

  // ---- fragment read: slab s (rows s*32+l31), swizzled chunks -------------
  const int sw = (l31 >> 1) & 3;
  auto read_frag = [&](const unsigned char* U, int s) -> i32x8 {
    const unsigned char* p =
        U + s * 2048 + (l31 >> 4) * 1024 + (l31 & 15) * 64;
    i32x4 lo = *reinterpret_cast<const i32x4*>(p + (((lh * 2)     ^ sw) << 4));
    i32x4 hi = *reinterpret_cast<const i32x4*>(p + (((lh * 2 + 1) ^ sw) << 4));
    return __builtin_shufflevector(lo, hi, 0, 1, 2, 3, 4, 5, 6, 7);
  };

  f32x16 acc[2][2];
#pragma unroll
  for (int mi = 0; mi < 2; ++mi)
#pragma unroll
    for (int ni = 0; ni < 2; ++ni)
#pragma unroll
      for (int r = 0; r < 16; ++r) acc[mi][ni][r] = 0.f;

  // ---- prologue: stage units 0..5 (tile0 + tile1's u0,u1) -----------------
  stage(0); stage(1); stage(2); stage(3); stage(4); stage(5);

  i32x8 af[2], bfr[2];

  for (int T = 0; T < NT; ++T) {
#pragma unroll
    for (int ks = 0; ks < 2; ++ks) {
      // phase top: wait for this phase's units, publish across waves
      if (T == NT - 1 && ks == 1)
        asm volatile("s_waitcnt vmcnt(0)" ::: "memory");
      else
        asm volatile("s_waitcnt vmcnt(4)" ::: "memory");
      __builtin_amdgcn_s_barrier();

      const int u0 = 4 * T + ks * 2;                 // this phase's units
      const unsigned char* aU = lds + (u0 % NSLOT) * 8192;
      const unsigned char* bU = lds + ((u0 + 1) % NSLOT) * 8192;
#pragma unroll
      for (int ni = 0; ni < 2; ++ni)
        bfr[ni] = read_frag(bU, wc * 2 + ni);
#pragma unroll
      for (int mi = 0; mi < 2; ++mi)
        af[mi] = read_frag(aU, wr * 2 + mi);
      __builtin_amdgcn_sched_barrier(0);            // reads issue first
      {
        const int sg = 4 * (T + 1) + ks * 2;        // stage next tile's pair
        if (sg < NUNITS) stage(sg);
        if (sg + 1 < NUNITS) stage(sg + 1);
      }
      asm volatile("s_waitcnt lgkmcnt(0)" ::: "memory");
      __builtin_amdgcn_sched_barrier(0);
      __builtin_amdgcn_s_setprio(1);
#pragma unroll
      for (int mi = 0; mi < 2; ++mi)
#pragma unroll
        for (int ni = 0; ni < 2; ++ni)
          acc[mi][ni] = __builtin_amdgcn_mfma_scale_f32_32x32x64_f8f6f4(
              af[mi], bfr[ni], acc[mi][ni],
              0, 0,            // cbsz=fp8, blgp=fp8
              0, SCALE1,       // A: opsel 0, scale 1.0
              0, SCALE1);      // B: opsel 0, scale 1.0
      __builtin_amdgcn_s_setprio(0);
    }
  }

  // ---- epilogue: per-row sum of exp(logit) over this wg's 128 vocab cols --
  // 32x32 C/D: col = lane&31, row = (reg&3) + 8*(reg>>2) + 4*(lane>>5).
  // Undo the C*8 pre-scale: logit = acc * 0.125.
#pragma unroll
  for (int mi = 0; mi < 2; ++mi) {
    float p[16];
#pragma unroll
    for (int r = 0; r < 16; ++r)
      p[r] = __expf(acc[mi][0][r] * 0.125f) + __expf(acc[mi][1][r] * 0.125f);
#pragma unroll
    for (int m = 1; m < 32; m <<= 1)
#pragma unroll
      for (int r = 0; r < 16; ++r) p[r] += __shfl_xor(p[r], m, 64);
    if (l31 == 0) {
#pragma unroll
      for (int r = 0; r < 16; ++r) {
        const int row = brow + wr * 64 + mi * 32 + (r & 3) + 8 * (r >> 2) + 4 * lh;
        atomicAdd(&sumexp[row], p[r]);
      }
    }
  }
}

// ---------------- fallback path (fp32 reg-staged, 128^2 tile) --------------
#define FBM 128
#define FBN 128
#define FBK 64
#define FNK (DIM / FBK)
#define FTHREADS 512

__global__ __launch_bounds__(FTHREADS, 4)
void lce_gemm_f32(const float* __restrict__ E, const float* __restrict__ C,
                  float* __restrict__ sumexp) {
  extern __shared__ unsigned char lds[];
  const int tid  = threadIdx.x;
  const int brow = blockIdx.x * FBM;
  const int bcol = blockIdx.y * FBN;

  float4 ra[4], rb[4];
  auto ld = [&](int k0) {
#pragma unroll
    for (int i = 0; i < 4; ++i) {
      int f = tid + i * FTHREADS;
      int r = f >> 4;
      int c = (f & 15) << 2;
      ra[i] = *reinterpret_cast<const float4*>(&E[(size_t)(brow + r) * DIM + k0 + c]);
      rb[i] = *reinterpret_cast<const float4*>(&C[(size_t)(bcol + r) * DIM + k0 + c]);
    }
  };
  auto st = [&](int buf) {
    unsigned char* a = lds + buf * 32768;
    unsigned char* b = a + 16384;
#pragma unroll
    for (int i = 0; i < 4; ++i) {
      int f  = tid + i * FTHREADS;
      int r  = f >> 4;
      int cbb = (f & 15) << 3;
      int off = r * 128 + (cbb ^ ((r & 7) << 4));
      union { bf16_t h[4]; unsigned long long u; } pa, pb;
      pa.h[0] = (bf16_t)ra[i].x; pa.h[1] = (bf16_t)ra[i].y;
      pa.h[2] = (bf16_t)ra[i].z; pa.h[3] = (bf16_t)ra[i].w;
      pb.h[0] = (bf16_t)rb[i].x; pb.h[1] = (bf16_t)rb[i].y;
      pb.h[2] = (bf16_t)rb[i].z; pb.h[3] = (bf16_t)rb[i].w;
      *reinterpret_cast<unsigned long long*>(a + off) = pa.u;
      *reinterpret_cast<unsigned long long*>(b + off) = pb.u;
    }
  };

  f32x4 acc[4][2];
#pragma unroll
  for (int mi = 0; mi < 4; ++mi)
#pragma unroll
    for (int ni = 0; ni < 2; ++ni) acc[mi][ni] = (f32x4){0.f, 0.f, 0.f, 0.f};

  const int lane = tid & 63, wid = tid >> 6;
  const int wr = wid >> 2, wc = wid & 3;
  const int l15 = lane & 15, lg = lane >> 4;
  const int swz = (l15 & 7) << 4;

  auto comp = [&](int buf) {
    const unsigned char* a = lds + buf * 32768;
    const unsigned char* b = a + 16384;
#pragma unroll
    for (int kk = 0; kk < 2; ++kk) {
      const int cbase = (kk * 64 + lg * 16) ^ swz;
      bf16x8 af[4], bfr[2];
#pragma unroll
      for (int mi = 0; mi < 4; ++mi)
        af[mi] = *reinterpret_cast<const bf16x8*>(
            a + (wr * 64 + mi * 16 + l15) * 128 + cbase);
#pragma unroll
      for (int ni = 0; ni < 2; ++ni)
        bfr[ni] = *reinterpret_cast<const bf16x8*>(
            b + (wc * 32 + ni * 16 + l15) * 128 + cbase);
#pragma unroll
      for (int mi = 0; mi < 4; ++mi)
#pragma unroll
        for (int ni = 0; ni < 2; ++ni)
          acc[mi][ni] = __builtin_amdgcn_mfma_f32_16x16x32_bf16(
              af[mi], bfr[ni], acc[mi][ni], 0, 0, 0);
    }
  };

  ld(0);
  st(0);
  for (int kt = 0; kt < FNK; ++kt) {
    __syncthreads();
    if (kt + 1 < FNK) ld((kt + 1) * FBK);
    comp(kt & 1);
    if (kt + 1 < FNK) st((kt + 1) & 1);
  }

#pragma unroll
  for (int mi = 0; mi < 4; ++mi) {
    float p[4];
#pragma unroll
    for (int j = 0; j < 4; ++j)
      p[j] = __expf(acc[mi][0][j]) + __expf(acc[mi][1][j]);
#pragma unroll
    for (int m = 1; m < 16; m <<= 1)
#pragma unroll
      for (int j = 0; j < 4; ++j) p[j] += __shfl_xor(p[j], m, 64);
    if (l15 == 0) {
      int row = brow + wr * 64 + mi * 16 + lg * 4;
#pragma unroll
      for (int j = 0; j < 4; ++j) atomicAdd(&sumexp[row + j], p[j]);
    }
  }
}

// ---------------- exact fp32 target logit, one wave per row ----------------
__global__ __launch_bounds__(256)
void lce_tgt(const float* __restrict__ E, const float* __restrict__ C,
             const int* __restrict__ T, float* __restrict__ tgt) {
  int w = (int)((blockIdx.x * blockDim.x + threadIdx.x) >> 6);
  int lane = threadIdx.x & 63;
  if (w >= N_ROWS) return;
  int t = T[w];
  float s = 0.f;
  if (t != IGN) {
    const float4* er = reinterpret_cast<const float4*>(E + (size_t)w * DIM);
    const float4* cr = reinterpret_cast<const float4*>(C + (size_t)t * DIM);
#pragma unroll
    for (int i = 0; i < DIM / 4 / 64; ++i) {
      float4 a = er[lane + i * 64];
      float4 b = cr[lane + i * 64];
      s = fmaf(a.x, b.x, s); s = fmaf(a.y, b.y, s);
      s = fmaf(a.z, b.z, s); s = fmaf(a.w, b.w, s);
    }
#pragma unroll
    for (int m = 1; m < 64; m <<= 1) s += __shfl_xor(s, m, 64);
  }
  if (lane == 0) tgt[w] = s;
}

// ---------------- final scalar reduce --------------------------------------
__global__ __launch_bounds__(256)
void lce_finalize(const float* __restrict__ sumexp, const float* __restrict__ tgt,
                  const int* __restrict__ T, float* __restrict__ out) {
  int tid = threadIdx.x;
  float nll = 0.f, cnt = 0.f;
  for (int n = tid; n < N_ROWS; n += 256) {
    if (T[n] != IGN) {
      nll += logf(sumexp[n]) - tgt[n];
      cnt += 1.f;
    }
  }
#pragma unroll
  for (int m = 1; m < 64; m <<= 1) {
    nll += __shfl_xor(nll, m, 64);
    cnt += __shfl_xor(cnt, m, 64);
  }
  __shared__ float sn[4], sc[4];
  if ((tid & 63) == 0) { sn[tid >> 6] = nll; sc[tid >> 6] = cnt; }
  __syncthreads();
  if (tid == 0) {
    float a = 0.f, b = 0.f;
#pragma unroll
    for (int i = 0; i < 4; ++i) { a += sn[i]; b += sc[i]; }
    out[0] = a / fmaxf(b, 1.f);
  }
}

extern "C" void kernel_launch(void* const* d_in, const int* in_sizes, int n_in,
                              void* d_out, int out_size, void* d_ws, size_t ws_size,
                              hipStream_t stream) {
  const float* E = (const float*)d_in[0];
  const float* C = (const float*)d_in[1];
  const int*   T = (const int*)d_in[2];
  float* out = (float*)d_out;

  unsigned char* ws = (unsigned char*)d_ws;
  float* sumexp = (float*)ws;                        // 16 KB
  float* tgt    = (float*)(ws + 16384);              // 16 KB
  unsigned char* E8 = ws + 32768;                    // 8 MB
  unsigned char* C8 = E8 + (size_t)N_ROWS * DIM;     // 128 MB

  const size_t need = 32768 + (size_t)N_ROWS * DIM + (size_t)VOCAB * DIM;

  hipMemsetAsync(sumexp, 0, N_ROWS * sizeof(float), stream);

  if (ws_size >= need) {
    cvt_fp8<<<2048, 256, 0, stream>>>(E, E8, (long)N_ROWS * DIM / 16, 1.0f);
    cvt_fp8<<<2048, 256, 0, stream>>>(C, C8, (long)VOCAB * DIM / 16, 8.0f);
    lce_gemm_fp8<<<dim3((N_ROWS / BM) * (VOCAB / BN)), 256, 49152, stream>>>(E8, C8, sumexp);
  } else {
    lce_gemm_f32<<<dim3(N_ROWS / FBM, VOCAB / FBN), FTHREADS, 65536, stream>>>(E, C, sumexp);
  }

  lce_tgt<<<dim3((N_ROWS * 64) / 256), 256, 0, stream>>>(E, C, T, tgt);
  lce_finalize<<<dim3(1), 256, 0, stream>>>(sumexp, tgt, T, out);
}

// Round 21
// 864.124 us; speedup vs baseline: 1.4380x; 1.0539x over previous
//
#include <hip/hip_runtime.h>
#include <hip/hip_bf16.h>
#include <hip/hip_fp8.h>

typedef __bf16 bf16_t;
typedef bf16_t bf16x8 __attribute__((ext_vector_type(8)));
typedef float f32x4 __attribute__((ext_vector_type(4)));
typedef float f32x16 __attribute__((ext_vector_type(16)));
typedef int   i32x4  __attribute__((ext_vector_type(4)));
typedef int   i32x8  __attribute__((ext_vector_type(8)));

#define N_ROWS 4096
#define DIM    2048
#define VOCAB  65536
#define IGN    (-100)

// ---------------- MX-fp8 256x256 GEMM, BK=128 (R10 config, best measured) --
#define BM 256
#define BN 256
#define BK 128            // fp8 elems (=bytes) per K-tile
#define NT (DIM / BK)     // 16 K-tiles
#define NUNITS (4 * NT)   // 64 stage units (16KB each)
#define SCALE1 0x7F7F7F7F // e8m0 = 127 -> 1.0 in every byte

#define GLOAD_LDS16(gp, lp)                                                  \
  __builtin_amdgcn_global_load_lds(                                          \
      (const __attribute__((address_space(1))) void*)(gp),                   \
      (__attribute__((address_space(3))) void*)(lp), 16, 0, 0)

// fp32 -> fp8 e4m3 (OCP) with pre-scale; 16 elems/thread/iter
__global__ __launch_bounds__(256)
void cvt_fp8(const float* __restrict__ src, unsigned char* __restrict__ dst,
             long n16, float scale) {
  long i = (long)blockIdx.x * 256 + threadIdx.x;
  long stride = (long)gridDim.x * 256;
  for (; i < n16; i += stride) {
    const float4* s = reinterpret_cast<const float4*>(src) + i * 4;
    union { unsigned char b[16]; i32x4 v; } o;
#pragma unroll
    for (int q = 0; q < 4; ++q) {
      float4 a = s[q];
      o.b[q * 4 + 0] = __hip_fp8_e4m3(a.x * scale).__x;
      o.b[q * 4 + 1] = __hip_fp8_e4m3(a.y * scale).__x;
      o.b[q * 4 + 2] = __hip_fp8_e4m3(a.z * scale).__x;
      o.b[q * 4 + 3] = __hip_fp8_e4m3(a.w * scale).__x;
    }
    *reinterpret_cast<i32x4*>(dst + i * 16) = o.v;
  }
}

// 256x256 tile, BK=128, 8 waves (2M x 4N, each 128x64 out), MX-fp8 MFMA
// (32x32x64, unity scales; C pre-scaled x8, undone via acc*0.125).
// Best-measured configuration (R10: GEMM 743-757us, total 866.9us).
// LDS 128KB = 8 slots x 16KB; unit u of tile T: 0=A[k0:64], 1=B[k0:64],
// 2=A[k64:128], 3=B[k64:128]. Unit layout: 16 windows of 1KB, window w =
// rows 16w..16w+15. Within a window, slot i holds global granule
// tau(i) = (i&~3) | ((i&3) ^ ((i>>3)&3))  (self-inverse 64-slot perm).
// Staging: gload_lds linear dest + per-lane permuted source (the 64 lanes
// cover the SAME contiguous 16x64B region as row-major -> coalesced).
// Reads: lane l31 reads row l31's chunk c at r16*64 + (c^((l31>>1)&3))*16.
// 2 phases/tile: {12 ds_read; stage 2 units; lgkm(0); 8 MFMA; [vmcnt];
// barrier}. P0 stages {4T+6,4T+7}, P1 {4T+8,4T+9}; vmcnt(4) at P1 end
// (vmcnt(0) at T=NT-2). Slot lifetimes verified.
// Plateau note (R8-R20): MfmaUtil ~32% is structural for this family --
// phase overhead ~2400cyc is invariant to barriers/prefetch-depth/
// occupancy/traffic/conflicts (13 variants, 743-1140us). Next levers
// would be instruction-level (hand-asm K-loop).
__global__ __launch_bounds__(512, 2)
void lce_gemm_fp8(const unsigned char* __restrict__ E8,
                  const unsigned char* __restrict__ C8,
                  float* __restrict__ sumexp) {
  extern __shared__ unsigned char lds[];  // 131072
  const int tid = threadIdx.x;
  const int lane = tid & 63, wid = tid >> 6;
  const int wr = wid >> 2, wc = wid & 3;      // 2M x 4N waves
  const int l31 = lane & 31, lh = lane >> 5;

  // bijective XCD swizzle (nwg=4096, %8==0), row-tile fast for C reuse
  const int bid = blockIdx.x;
  const int wg = (bid & 7) * (((N_ROWS / BM) * (VOCAB / BN)) / 8) + (bid >> 3);
  const int brow = (wg & (N_ROWS / BM - 1)) * BM;
  const int bcol = (wg / (N_ROWS / BM)) * BN;

  // ---- staging: per-thread 2 granules of 16B ------------------------------
  const int g0 = wid * 64 + lane;         // granule 0..511 (window = wid)
  const int g1 = 512 + g0;                // granule 512..1023
  const int prel0 = g0 * 16;              // linear LDS dest
  const int prel1 = g1 * 16;
  auto mkgoff = [&](int g) {              // window-permuted global source
    int w = g >> 6, i = g & 63;
    return (size_t)(w * 16 + (i >> 2)) * DIM +
           (size_t)((((i & 3) ^ ((i >> 3) & 3)) << 4));
  };
  const size_t goff0 = mkgoff(g0), goff1 = mkgoff(g1);

  const unsigned char* Ebase = E8 + (size_t)brow * DIM;
  const unsigned char* Cbase = C8 + (size_t)bcol * DIM;

  auto stage = [&](int ug) {   // ug = global unit index [0, NUNITS)
    const unsigned char* gb = ((ug & 1) ? Cbase : Ebase) +
                              (ug >> 2) * BK + ((ug >> 1) & 1) * 64;
    unsigned char* lb = lds + (ug & 7) * 16384;     // slot = ug mod 8
    GLOAD_LDS16(gb + goff0, lb + prel0);
    GLOAD_LDS16(gb + goff1, lb + prel1);
  };

  // ---- fragment read: slab s (rows s*32+l31), swizzled chunks -------------
  const int sw = (l31 >> 1) & 3;
  auto read_frag = [&](const unsigned char* U, int s) -> i32x8 {
    const unsigned char* p =
        U + s * 2048 + (l31 >> 4) * 1024 + (l31 & 15) * 64;
    i32x4 lo = *reinterpret_cast<const i32x4*>(p + (((lh * 2)     ^ sw) << 4));
    i32x4 hi = *reinterpret_cast<const i32x4*>(p + (((lh * 2 + 1) ^ sw) << 4));
    return __builtin_shufflevector(lo, hi, 0, 1, 2, 3, 4, 5, 6, 7);
  };

  f32x16 acc[4][2];
#pragma unroll
  for (int mi = 0; mi < 4; ++mi)
#pragma unroll
    for (int ni = 0; ni < 2; ++ni)
#pragma unroll
      for (int r = 0; r < 16; ++r) acc[mi][ni][r] = 0.f;

  // ---- prologue: units 0..5 in flight, first 4 landed ---------------------
  stage(0); stage(1); stage(2); stage(3); stage(4); stage(5);
  asm volatile("s_waitcnt vmcnt(4)" ::: "memory");  // units 0..3 landed
  __builtin_amdgcn_s_barrier();

  i32x8 af[4], bfr[2];

  for (int T = 0; T < NT; ++T) {
    const unsigned char* base = lds + (T & 1) * 65536;
#pragma unroll
    for (int ks = 0; ks < 2; ++ks) {
      const unsigned char* aU = base + ks * 32768;
      const unsigned char* bU = aU + 16384;
#pragma unroll
      for (int ni = 0; ni < 2; ++ni)
        bfr[ni] = read_frag(bU, wc * 2 + ni);
#pragma unroll
      for (int mi = 0; mi < 4; ++mi)
        af[mi] = read_frag(aU, wr * 4 + mi);
      __builtin_amdgcn_sched_barrier(0);            // reads issue first
      const int ug = 4 * T + 6 + ks * 2;
      if (ug < NUNITS) stage(ug);
      if (ug + 1 < NUNITS) stage(ug + 1);
      asm volatile("s_waitcnt lgkmcnt(0)" ::: "memory");
      __builtin_amdgcn_sched_barrier(0);
      __builtin_amdgcn_s_setprio(1);
#pragma unroll
      for (int mi = 0; mi < 4; ++mi)
#pragma unroll
        for (int ni = 0; ni < 2; ++ni)
          acc[mi][ni] = __builtin_amdgcn_mfma_scale_f32_32x32x64_f8f6f4(
              af[mi], bfr[ni], acc[mi][ni],
              0, 0,            // cbsz=fp8, blgp=fp8
              0, SCALE1,       // A: opsel 0, scale 1.0
              0, SCALE1);      // B: opsel 0, scale 1.0
      __builtin_amdgcn_s_setprio(0);
      if (ks == 1 && T < NT - 1) {
        if (T < NT - 2) asm volatile("s_waitcnt vmcnt(4)" ::: "memory");
        else            asm volatile("s_waitcnt vmcnt(0)" ::: "memory");
      }
      __builtin_amdgcn_s_barrier();
    }
  }

  // ---- epilogue: per-row sum of exp(logit) over 256 vocab cols ------------
  // 32x32 C/D: col = lane&31, row = (reg&3) + 8*(reg>>2) + 4*(lane>>5).
  // Undo the C*8 pre-scale: logit = acc * 0.125.
#pragma unroll
  for (int mi = 0; mi < 4; ++mi) {
    float p[16];
#pragma unroll
    for (int r = 0; r < 16; ++r)
      p[r] = __expf(acc[mi][0][r] * 0.125f) + __expf(acc[mi][1][r] * 0.125f);
#pragma unroll
    for (int m = 1; m < 32; m <<= 1)
#pragma unroll
      for (int r = 0; r < 16; ++r) p[r] += __shfl_xor(p[r], m, 64);
    if (l31 == 0) {
#pragma unroll
      for (int r = 0; r < 16; ++r) {
        const int row = brow + wr * 128 + mi * 32 + (r & 3) + 8 * (r >> 2) + 4 * lh;
        atomicAdd(&sumexp[row], p[r]);
      }
    }
  }
}

// ---------------- fallback path (fp32 reg-staged, 128^2 tile) --------------
#define FBM 128
#define FBN 128
#define FBK 64
#define FNK (DIM / FBK)
#define FTHREADS 512

__global__ __launch_bounds__(FTHREADS, 4)
void lce_gemm_f32(const float* __restrict__ E, const float* __restrict__ C,
                  float* __restrict__ sumexp) {
  extern __shared__ unsigned char lds[];
  const int tid  = threadIdx.x;
  const int brow = blockIdx.x * FBM;
  const int bcol = blockIdx.y * FBN;

  float4 ra[4], rb[4];
  auto ld = [&](int k0) {
#pragma unroll
    for (int i = 0; i < 4; ++i) {
      int f = tid + i * FTHREADS;
      int r = f >> 4;
      int c = (f & 15) << 2;
      ra[i] = *reinterpret_cast<const float4*>(&E[(size_t)(brow + r) * DIM + k0 + c]);
      rb[i] = *reinterpret_cast<const float4*>(&C[(size_t)(bcol + r) * DIM + k0 + c]);
    }
  };
  auto st = [&](int buf) {
    unsigned char* a = lds + buf * 32768;
    unsigned char* b = a + 16384;
#pragma unroll
    for (int i = 0; i < 4; ++i) {
      int f  = tid + i * FTHREADS;
      int r  = f >> 4;
      int cbb = (f & 15) << 3;
      int off = r * 128 + (cbb ^ ((r & 7) << 4));
      union { bf16_t h[4]; unsigned long long u; } pa, pb;
      pa.h[0] = (bf16_t)ra[i].x; pa.h[1] = (bf16_t)ra[i].y;
      pa.h[2] = (bf16_t)ra[i].z; pa.h[3] = (bf16_t)ra[i].w;
      pb.h[0] = (bf16_t)rb[i].x; pb.h[1] = (bf16_t)rb[i].y;
      pb.h[2] = (bf16_t)rb[i].z; pb.h[3] = (bf16_t)rb[i].w;
      *reinterpret_cast<unsigned long long*>(a + off) = pa.u;
      *reinterpret_cast<unsigned long long*>(b + off) = pb.u;
    }
  };

  f32x4 acc[4][2];
#pragma unroll
  for (int mi = 0; mi < 4; ++mi)
#pragma unroll
    for (int ni = 0; ni < 2; ++ni) acc[mi][ni] = (f32x4){0.f, 0.f, 0.f, 0.f};

  const int lane = tid & 63, wid = tid >> 6;
  const int wr = wid >> 2, wc = wid & 3;
  const int l15 = lane & 15, lg = lane >> 4;
  const int swz = (l15 & 7) << 4;

  auto comp = [&](int buf) {
    const unsigned char* a = lds + buf * 32768;
    const unsigned char* b = a + 16384;
#pragma unroll
    for (int kk = 0; kk < 2; ++kk) {
      const int cbase = (kk * 64 + lg * 16) ^ swz;
      bf16x8 af[4], bfr[2];
#pragma unroll
      for (int mi = 0; mi < 4; ++mi)
        af[mi] = *reinterpret_cast<const bf16x8*>(
            a + (wr * 64 + mi * 16 + l15) * 128 + cbase);
#pragma unroll
      for (int ni = 0; ni < 2; ++ni)
        bfr[ni] = *reinterpret_cast<const bf16x8*>(
            b + (wc * 32 + ni * 16 + l15) * 128 + cbase);
#pragma unroll
      for (int mi = 0; mi < 4; ++mi)
#pragma unroll
        for (int ni = 0; ni < 2; ++ni)
          acc[mi][ni] = __builtin_amdgcn_mfma_f32_16x16x32_bf16(
              af[mi], bfr[ni], acc[mi][ni], 0, 0, 0);
    }
  };

  ld(0);
  st(0);
  for (int kt = 0; kt < FNK; ++kt) {
    __syncthreads();
    if (kt + 1 < FNK) ld((kt + 1) * FBK);
    comp(kt & 1);
    if (kt + 1 < FNK) st((kt + 1) & 1);
  }

#pragma unroll
  for (int mi = 0; mi < 4; ++mi) {
    float p[4];
#pragma unroll
    for (int j = 0; j < 4; ++j)
      p[j] = __expf(acc[mi][0][j]) + __expf(acc[mi][1][j]);
#pragma unroll
    for (int m = 1; m < 16; m <<= 1)
#pragma unroll
      for (int j = 0; j < 4; ++j) p[j] += __shfl_xor(p[j], m, 64);
    if (l15 == 0) {
      int row = brow + wr * 64 + mi * 16 + lg * 4;
#pragma unroll
      for (int j = 0; j < 4; ++j) atomicAdd(&sumexp[row + j], p[j]);
    }
  }
}

// ---------------- exact fp32 target logit, one wave per row ----------------
__global__ __launch_bounds__(256)
void lce_tgt(const float* __restrict__ E, const float* __restrict__ C,
             const int* __restrict__ T, float* __restrict__ tgt) {
  int w = (int)((blockIdx.x * blockDim.x + threadIdx.x) >> 6);
  int lane = threadIdx.x & 63;
  if (w >= N_ROWS) return;
  int t = T[w];
  float s = 0.f;
  if (t != IGN) {
    const float4* er = reinterpret_cast<const float4*>(E + (size_t)w * DIM);
    const float4* cr = reinterpret_cast<const float4*>(C + (size_t)t * DIM);
#pragma unroll
    for (int i = 0; i < DIM / 4 / 64; ++i) {
      float4 a = er[lane + i * 64];
      float4 b = cr[lane + i * 64];
      s = fmaf(a.x, b.x, s); s = fmaf(a.y, b.y, s);
      s = fmaf(a.z, b.z, s); s = fmaf(a.w, b.w, s);
    }
#pragma unroll
    for (int m = 1; m < 64; m <<= 1) s += __shfl_xor(s, m, 64);
  }
  if (lane == 0) tgt[w] = s;
}

// ---------------- final scalar reduce --------------------------------------
__global__ __launch_bounds__(256)
void lce_finalize(const float* __restrict__ sumexp, const float* __restrict__ tgt,
                  const int* __restrict__ T, float* __restrict__ out) {
  int tid = threadIdx.x;
  float nll = 0.f, cnt = 0.f;
  for (int n = tid; n < N_ROWS; n += 256) {
    if (T[n] != IGN) {
      nll += logf(sumexp[n]) - tgt[n];
      cnt += 1.f;
    }
  }
#pragma unroll
  for (int m = 1; m < 64; m <<= 1) {
    nll += __shfl_xor(nll, m, 64);
    cnt += __shfl_xor(cnt, m, 64);
  }
  __shared__ float sn[4], sc[4];
  if ((tid & 63) == 0) { sn[tid >> 6] = nll; sc[tid >> 6] = cnt; }
  __syncthreads();
  if (tid == 0) {
    float a = 0.f, b = 0.f;
#pragma unroll
    for (int i = 0; i < 4; ++i) { a += sn[i]; b += sc[i]; }
    out[0] = a / fmaxf(b, 1.f);
  }
}

extern "C" void kernel_launch(void* const* d_in, const int* in_sizes, int n_in,
                              void* d_out, int out_size, void* d_ws, size_t ws_size,
                              hipStream_t stream) {
  const float* E = (const float*)d_in[0];
  const float* C = (const float*)d_in[1];
  const int*   T = (const int*)d_in[2];
  float* out = (float*)d_out;

  unsigned char* ws = (unsigned char*)d_ws;
  float* sumexp = (float*)ws;                        // 16 KB
  float* tgt    = (float*)(ws + 16384);              // 16 KB
  unsigned char* E8 = ws + 32768;                    // 8 MB
  unsigned char* C8 = E8 + (size_t)N_ROWS * DIM;     // 128 MB

  const size_t need = 32768 + (size_t)N_ROWS * DIM + (size_t)VOCAB * DIM;

  hipMemsetAsync(sumexp, 0, N_ROWS * sizeof(float), stream);

  if (ws_size >= need) {
    cvt_fp8<<<2048, 256, 0, stream>>>(E, E8, (long)N_ROWS * DIM / 16, 1.0f);
    cvt_fp8<<<2048, 256, 0, stream>>>(C, C8, (long)VOCAB * DIM / 16, 8.0f);
    lce_gemm_fp8<<<dim3((N_ROWS / BM) * (VOCAB / BN)), 512, 131072, stream>>>(E8, C8, sumexp);
  } else {
    lce_gemm_f32<<<dim3(N_ROWS / FBM, VOCAB / FBN), FTHREADS, 65536, stream>>>(E, C, sumexp);
  }

  lce_tgt<<<dim3((N_ROWS * 64) / 256), 256, 0, stream>>>(E, C, T, tgt);
  lce_finalize<<<dim3(1), 256, 0, stream>>>(sumexp, tgt, T, out);
}